// Round 14
// baseline (404.335 us; speedup 1.0000x reference)
//
#include <hip/hip_runtime.h>
#include <stdint.h>

// B=64, C=512, H=W=32 -> N=65536 pixels, m=512 slots, d=512 dims.
// Inputs f32: query (33,554,432 elems), keys (262,144) -- selected by size.
// Output f32 concat: updated_query [64][1024][32][32] | updated_memory [512][512]
//   | score_query [65536][512] | score_memory [65536][512] | g_loss | s_loss
//
// R14 = R13 + K2f tile 64->128 rows/block (512 blocks): 32 MFMA/wave/K-step
// (amortizes B staging + barriers 2x). Epilogue extended to 128 rows; arrays
// overlay staging buffers. K1/K6f/K7 etc byte-identical to R13.

typedef unsigned int u32;
typedef unsigned long long u64;
typedef unsigned short u16;

typedef float f32x4 __attribute__((ext_vector_type(4)));
typedef short bf16x8 __attribute__((ext_vector_type(8)));

#define DIMS 512

__device__ __forceinline__ u16 f2bf(float x){
  u32 u = __float_as_uint(x);
  return (u16)((u + 0x7FFFu + ((u >> 16) & 1u)) >> 16);
}
__device__ __forceinline__ float bf2f(u16 h){ return __uint_as_float(((u32)h) << 16); }
__device__ __forceinline__ u32 pack2(float a, float b){
  return (u32)f2bf(a) | ((u32)f2bf(b) << 16);
}
__device__ __forceinline__ u32 fkey(float x){
  u32 b = __float_as_uint(x);
  return (b & 0x80000000u) ? ~b : (b | 0x80000000u);
}
__device__ __forceinline__ float fdec(u32 u){
  return (u & 0x80000000u) ? __uint_as_float(u & 0x7FFFFFFFu) : __uint_as_float(~u);
}
// async global->LDS, 16 B per lane (wave-level: LDS dest = base + lane*16)
__device__ __forceinline__ void gload16(char* lds, const void* g){
  __builtin_amdgcn_global_load_lds(
      (const __attribute__((address_space(1))) u32*)g,
      (__attribute__((address_space(3))) u32*)lds, 16, 0, 0);
}

// ---- K0: keys prep. 512 blocks x 512 threads.
__global__ __launch_bounds__(512) void k0_prep(const float* __restrict__ keys,
    u16* __restrict__ kb, u16* __restrict__ kt,
    float* __restrict__ kn2, float* __restrict__ ksum,
    u32* __restrict__ colmax_u, float* __restrict__ colsum)
{
  const int j = blockIdx.x, t = threadIdx.x;
  float v = keys[(size_t)j * 512 + t];
  u16 h = f2bf(v);
  kb[(size_t)j * 512 + t] = h;
  kt[(size_t)t * 512 + j] = h;
  float s = v, ss = v * v;
  #pragma unroll
  for (int d = 1; d < 64; d <<= 1){ s += __shfl_xor(s, d); ss += __shfl_xor(ss, d); }
  __shared__ float rs[8], rss[8];
  const int w = t >> 6, lane = t & 63;
  if (lane == 0){ rs[w] = s; rss[w] = ss; }
  __syncthreads();
  if (t == 0){
    float S = 0.f, SS = 0.f;
    for (int i = 0; i < 8; ++i){ S += rs[i]; SS += rss[i]; }
    ksum[j] = S; kn2[j] = SS;
  }
  if (j == 0){ colmax_u[t] = 0u; colsum[t] = 0.f; }
}

// ---- K1: channel L2-normalize, fully vectorized (float4 over pixels).
__global__ __launch_bounds__(256) void k1_norm(const float* __restrict__ query,
    float* __restrict__ uq, u16* __restrict__ qb, float* __restrict__ sumq)
{
  __shared__ float red[16][64];
  __shared__ float rinvS[64];
  __shared__ float T[64][65];
  const int t = threadIdx.x;
  const int px = (t & 15) * 4;
  const int cg = t >> 4;
  const int b = blockIdx.y;
  const int p0 = blockIdx.x * 64;
  const float* base = query + (size_t)b * 524288 + p0;

  float4 v4[32];
  float ssq0 = 0.f, ssq1 = 0.f, ssq2 = 0.f, ssq3 = 0.f;
  #pragma unroll
  for (int k = 0; k < 32; ++k){
    float4 x = *(const float4*)(base + (size_t)(cg + 16 * k) * 1024 + px);
    v4[k] = x;
    ssq0 += x.x * x.x; ssq1 += x.y * x.y; ssq2 += x.z * x.z; ssq3 += x.w * x.w;
  }
  red[cg][px]     = ssq0;
  red[cg][px + 1] = ssq1;
  red[cg][px + 2] = ssq2;
  red[cg][px + 3] = ssq3;
  __syncthreads();
  if (t < 64){
    float tot = 0.f;
    #pragma unroll
    for (int g = 0; g < 16; ++g) tot += red[g][t];
    rinvS[t] = 1.0f / fmaxf(sqrtf(tot), 1e-12f);
  }
  __syncthreads();
  const float4 ri = *(const float4*)(&rinvS[px]);
  float* uqo = uq + (size_t)b * 1048576 + p0;
  float ms0 = 0.f, ms1 = 0.f, ms2 = 0.f, ms3 = 0.f;
  #pragma unroll
  for (int k = 0; k < 32; ++k){
    float4 x = v4[k];
    x.x *= ri.x; x.y *= ri.y; x.z *= ri.z; x.w *= ri.w;
    v4[k] = x;
    *(float4*)(uqo + (size_t)(cg + 16 * k) * 1024 + px) = x;
    ms0 += x.x; ms1 += x.y; ms2 += x.z; ms3 += x.w;
  }
  const int r = t >> 2, seg = t & 3;
  for (int cb = 0; cb < 8; ++cb){
    #pragma unroll
    for (int m = 0; m < 4; ++m){
      float4 x = v4[cb * 4 + m];
      float* Trow = &T[cg + 16 * m][px];
      Trow[0] = x.x; Trow[1] = x.y; Trow[2] = x.z; Trow[3] = x.w;
    }
    __syncthreads();
    {
      u32 wpk[8];
      #pragma unroll
      for (int k = 0; k < 8; ++k)
        wpk[k] = pack2(T[seg * 16 + 2 * k][r], T[seg * 16 + 2 * k + 1][r]);
      uint4* dst = (uint4*)(qb + ((size_t)(b * 1024 + p0 + r)) * 512 + cb * 64 + seg * 16);
      dst[0] = make_uint4(wpk[0], wpk[1], wpk[2], wpk[3]);
      dst[1] = make_uint4(wpk[4], wpk[5], wpk[6], wpk[7]);
    }
    __syncthreads();
  }
  red[cg][px]     = ms0;
  red[cg][px + 1] = ms1;
  red[cg][px + 2] = ms2;
  red[cg][px + 3] = ms3;
  __syncthreads();
  if (t < 64){
    float tot = 0.f;
    #pragma unroll
    for (int g = 0; g < 16; ++g) tot += red[g][t];
    sumq[(size_t)b * 1024 + p0 + t] = tot;
  }
}

// ---- K2f: fused score GEMM + row stats + SM + col atomics + losses.
// 512 blocks x 512 threads (8 waves). 128 N-rows x all 512 slots, BK=32,
// double-buffered LDS, ONE barrier per K-step. 32 MFMA/wave/step.
// LDS: As0 @0 (8K), As1 @8192, Bs0 @16384 (32K), Bs1 @49152 = 80 KB.
// Epilogue arrays overlay As0/Bs0 region (dead after last step reads buf1).
__global__ __launch_bounds__(512) void k2f(const u16* __restrict__ Aq,
    const u16* __restrict__ Bk, float* __restrict__ SM,
    u32* __restrict__ colmax_u, float* __restrict__ colsum,
    int* __restrict__ gidx, float* __restrict__ s1v, float* __restrict__ rfac,
    const float* __restrict__ kn2, const float* __restrict__ ksum,
    const float* __restrict__ sumq, float* __restrict__ part)
{
  __shared__ __align__(16) char smem[81920];
  const int t = threadIdx.x;
  const int w = t >> 6;
  const int lane = t & 63;
  const int l15 = lane & 15, l4 = lane >> 4;
  const int n0 = blockIdx.x * 128;

  f32x4 acc[8][4];
  #pragma unroll
  for (int a = 0; a < 8; ++a)
    #pragma unroll
    for (int b = 0; b < 4; ++b) acc[a][b] = (f32x4){0.f, 0.f, 0.f, 0.f};

  // staging sources (pre-swizzled), chunk = 1024 B = 16 rows
  const int lrow = lane >> 2;
  const int lpos = lane & 3;
  const u16* srcB[4];
  #pragma unroll
  for (int i = 0; i < 4; ++i){
    int r = w * 64 + i * 16 + lrow;
    srcB[i] = Bk + (size_t)r * 512 + ((lpos ^ ((r >> 1) & 3)) * 8);
  }
  const u16* srcA;   // 8 waves x 1 chunk = 128 rows
  {
    int r = w * 16 + lrow;
    srcA = Aq + (size_t)(n0 + r) * 512 + ((lpos ^ ((r >> 1) & 3)) * 8);
  }

  // prologue: stage tile 0 -> buf0
  {
    char* ldsB = smem + 16384 + w * 4096;
    #pragma unroll
    for (int i = 0; i < 4; ++i) gload16(ldsB + i * 1024, srcB[i]);
    gload16(smem + w * 1024, srcA);
  }
  __syncthreads();

  for (int kk = 0; kk < 16; ++kk){
    const int cur = kk & 1;
    if (kk < 15){
      const int nxt = cur ^ 1;
      const int ko = (kk + 1) * 32;
      char* ldsB = smem + 16384 + nxt * 32768 + w * 4096;
      #pragma unroll
      for (int i = 0; i < 4; ++i) gload16(ldsB + i * 1024, srcB[i] + ko);
      gload16(smem + nxt * 8192 + w * 1024, srcA + ko);
    }
    const char* As = smem + cur * 8192;
    const char* Bs = smem + 16384 + cur * 32768;
    bf16x8 af[8], bf[4];
    #pragma unroll
    for (int mi = 0; mi < 8; ++mi){
      int rr = mi * 16 + l15;
      af[mi] = *(const bf16x8*)(As + rr * 64 + ((l4 ^ ((rr >> 1) & 3)) * 16));
    }
    #pragma unroll
    for (int nj = 0; nj < 4; ++nj){
      int rb = w * 64 + nj * 16 + l15;
      bf[nj] = *(const bf16x8*)(Bs + rb * 64 + ((l4 ^ ((rb >> 1) & 3)) * 16));
    }
    #pragma unroll
    for (int mi = 0; mi < 8; ++mi)
      #pragma unroll
      for (int nj = 0; nj < 4; ++nj)
        acc[mi][nj] = __builtin_amdgcn_mfma_f32_16x16x32_bf16(af[mi], bf[nj], acc[mi][nj], 0, 0, 0);
    __syncthreads();
  }

  // epilogue LDS overlays staging region: need 5 x [8][128] f32/int (4KB each) + rtinv
  float* rs_m1 = (float*)(smem);            // [8][128] = 4096 B
  float* rs_m2 = (float*)(smem + 4096);
  float* rs_es = (float*)(smem + 8192);
  int*   rs_i1 = (int*)(smem + 12288);
  int*   rs_i2 = (int*)(smem + 16384);
  float* rtinv = (float*)(smem + 20480);    // [128]

  // acc[mi][nj][e]: row = mi*16 + l4*4 + e (N, 0..127), col = w*64 + nj*16 + l15.
  #pragma unroll
  for (int mi = 0; mi < 8; ++mi){
    #pragma unroll
    for (int e = 0; e < 4; ++e){
      const int row = mi * 16 + l4 * 4 + e;
      float m1 = -3e38f, m2 = -3e38f; int i1 = 0x7FFFFFFF, i2 = 0x7FFFFFFF;
      #pragma unroll
      for (int nj = 0; nj < 4; ++nj){
        float val = acc[mi][nj][e];
        int idx = w * 64 + nj * 16 + l15;
        if (val > m1){ m2 = m1; i2 = i1; m1 = val; i1 = idx; }
        else if (val > m2){ m2 = val; i2 = idx; }
      }
      #pragma unroll
      for (int d = 1; d < 16; d <<= 1){
        float o1 = __shfl_xor(m1, d), o2 = __shfl_xor(m2, d);
        int oi1 = __shfl_xor(i1, d), oi2 = __shfl_xor(i2, d);
        if (o1 > m1 || (o1 == m1 && oi1 < i1)){
          if (m1 > o2 || (m1 == o2 && i1 < oi2)){ m2 = m1; i2 = i1; }
          else { m2 = o2; i2 = oi2; }
          m1 = o1; i1 = oi1;
        } else {
          if (o1 > m2 || (o1 == m2 && oi1 < i2)){ m2 = o1; i2 = oi1; }
        }
      }
      if (l15 == 0){
        rs_m1[w * 128 + row] = m1; rs_i1[w * 128 + row] = i1;
        rs_m2[w * 128 + row] = m2; rs_i2[w * 128 + row] = i2;
      }
    }
  }
  #pragma unroll
  for (int nj = 0; nj < 4; ++nj){
    float cm = -3e38f;
    #pragma unroll
    for (int mi = 0; mi < 8; ++mi)
      #pragma unroll
      for (int e = 0; e < 4; ++e) cm = fmaxf(cm, acc[mi][nj][e]);
    cm = fmaxf(cm, __shfl_xor(cm, 16));
    cm = fmaxf(cm, __shfl_xor(cm, 32));
    if (l4 == 0) atomicMax(&colmax_u[w * 64 + nj * 16 + l15], fkey(cm));
  }
  #pragma unroll
  for (int mi = 0; mi < 8; ++mi)
    #pragma unroll
    for (int nj = 0; nj < 4; ++nj)
      #pragma unroll
      for (int e = 0; e < 4; ++e) acc[mi][nj][e] = expf(acc[mi][nj][e]);
  #pragma unroll
  for (int mi = 0; mi < 8; ++mi){
    #pragma unroll
    for (int e = 0; e < 4; ++e){
      const int row = mi * 16 + l4 * 4 + e;
      float ps = acc[mi][0][e] + acc[mi][1][e] + acc[mi][2][e] + acc[mi][3][e];
      #pragma unroll
      for (int d = 1; d < 16; d <<= 1) ps += __shfl_xor(ps, d);
      if (l15 == 0) rs_es[w * 128 + row] = ps;
    }
  }
  #pragma unroll
  for (int nj = 0; nj < 4; ++nj){
    float cs = 0.f;
    #pragma unroll
    for (int mi = 0; mi < 8; ++mi)
      #pragma unroll
      for (int e = 0; e < 4; ++e) cs += acc[mi][nj][e];
    cs += __shfl_xor(cs, 16);
    cs += __shfl_xor(cs, 32);
    if (l4 == 0) atomicAdd(&colsum[w * 64 + nj * 16 + l15], cs);
  }
  __syncthreads();
  if (t < 128){
    const int row = t, n = n0 + row;
    float m1 = -3e38f, m2 = -3e38f; int i1 = 0x7FFFFFFF, i2 = 0x7FFFFFFF;
    float tot = 0.f;
    #pragma unroll
    for (int w2 = 0; w2 < 8; ++w2){
      float o1 = rs_m1[w2 * 128 + row], o2 = rs_m2[w2 * 128 + row];
      int oi1 = rs_i1[w2 * 128 + row], oi2 = rs_i2[w2 * 128 + row];
      tot += rs_es[w2 * 128 + row];
      if (o1 > m1 || (o1 == m1 && oi1 < i1)){
        if (m1 > o2 || (m1 == o2 && i1 < oi2)){ m2 = m1; i2 = i1; }
        else { m2 = o2; i2 = oi2; }
        m1 = o1; i1 = oi1;
      } else {
        if (o1 > m2 || (o1 == m2 && oi1 < i2)){ m2 = o1; i2 = oi1; }
      }
    }
    gidx[n] = i1; s1v[n] = m1; rfac[n] = tot;
    rtinv[row] = 1.0f / tot;
    float sq = sumq[n];
    float gl = 1.0f + kn2[i1] - 2.0f * m1;
    float dp2 = gl + 2e-6f * (sq - ksum[i1]) + 5.12e-10f;
    float dn2 = 1.0f + kn2[i2] - 2.0f * m2 + 2e-6f * (sq - ksum[i2]) + 5.12e-10f;
    float sl = fmaxf(sqrtf(dp2) - sqrtf(dn2) + 1.0f, 0.0f);
    #pragma unroll
    for (int d = 1; d < 64; d <<= 1){ gl += __shfl_xor(gl, d); sl += __shfl_xor(sl, d); }
    // lane 0 of wave 0 and wave 1 each hold a 64-row subtotal
    if ((t & 63) == 0){
      atomicAdd(&part[2 * blockIdx.x], gl);
      atomicAdd(&part[2 * blockIdx.x + 1], sl);
    }
  }
  __syncthreads();
  #pragma unroll
  for (int mi = 0; mi < 8; ++mi){
    #pragma unroll
    for (int e = 0; e < 4; ++e){
      const int row = mi * 16 + l4 * 4 + e;
      const float ri = rtinv[row];
      float* dst = SM + (size_t)(n0 + row) * 512 + w * 64 + l15;
      #pragma unroll
      for (int nj = 0; nj < 4; ++nj)
        dst[nj * 16] = acc[mi][nj][e] * ri;
    }
  }
}

// ---- Kz: zero the loss partials (K2f accumulates via atomicAdd now).
__global__ __launch_bounds__(256) void kz_zero(float* __restrict__ part){
  part[blockIdx.x * 256 + threadIdx.x] = 0.f;
}

// ---- K7: memory update, 512 threads (8 waves x 8192 rows). wgt = exp(s1 - cm).
__global__ __launch_bounds__(512) void k7_update(const int* __restrict__ gidx,
    const float* __restrict__ s1v, const u32* __restrict__ colmax_u,
    const u16* __restrict__ qb, const float* __restrict__ keys, float* __restrict__ um)
{
  const int j = blockIdx.x;
  const int t = threadIdx.x;
  const int lane = t & 63;
  const int w = t >> 6;
  const float cm = fdec(colmax_u[j]);
  float acc[8] = {0.f, 0.f, 0.f, 0.f, 0.f, 0.f, 0.f, 0.f};
  const int b0 = w * 8192, b1 = b0 + 8192;
  for (int base = b0; base < b1; base += 64){
    u64 mask = __ballot(gidx[base + lane] == j);
    while (mask){
      int bpos = (int)__builtin_ctzll(mask);
      mask &= mask - 1;
      int rrow = base + bpos;
      float wgt = expf(s1v[rrow] - cm);
      uint4 rv = *(const uint4*)(qb + (size_t)rrow * 512 + lane * 8);
      u32 a4[4] = {rv.x, rv.y, rv.z, rv.w};
      #pragma unroll
      for (int q = 0; q < 4; ++q){
        acc[2 * q]     += wgt * bf2f((u16)(a4[q] & 0xFFFFu));
        acc[2 * q + 1] += wgt * bf2f((u16)(a4[q] >> 16));
      }
    }
  }
  __shared__ float red[512];
  red[t] = 0.f;
  __syncthreads();
  #pragma unroll
  for (int k = 0; k < 8; ++k) atomicAdd(&red[lane * 8 + k], acc[k]);
  __syncthreads();
  float v0 = red[t] + keys[(size_t)j * 512 + t];
  float ssq = v0 * v0;
  #pragma unroll
  for (int d = 1; d < 64; d <<= 1) ssq += __shfl_xor(ssq, d);
  __shared__ float rr8[8];
  if (lane == 0) rr8[w] = ssq;
  __syncthreads();
  float tot = rr8[0] + rr8[1] + rr8[2] + rr8[3] + rr8[4] + rr8[5] + rr8[6] + rr8[7];
  const float rinv = 1.0f / fmaxf(sqrtf(tot), 1e-12f);
  um[(size_t)j * 512 + t] = v0 * rinv;
}

// ---- K6f: concat GEMM + SQ side-write. 1024 blocks x 512 threads, double-buffered,
// one barrier per K-step. A = kt (gload_lds), B = SM f32->bf16 (depth-2 reg pipeline).
__global__ __launch_bounds__(512) void k6f(const float* __restrict__ SMf,
    const u16* __restrict__ kt, float* __restrict__ Uq, float* __restrict__ SQ,
    const float* __restrict__ rfac, const float* __restrict__ colsum)
{
  // Ks0 @0 (32K), Ks1 @32768, Qs0 @65536 (4K), Qs1 @69632  = 72 KB
  __shared__ __align__(16) char smem[73728];
  const int t = threadIdx.x;
  const int w = t >> 6;
  const int lane = t & 63;
  const int l15 = lane & 15, l4 = lane >> 4;
  const int n0 = blockIdx.x * 64;

  f32x4 acc[4][4];
  #pragma unroll
  for (int a = 0; a < 4; ++a)
    #pragma unroll
    for (int b = 0; b < 4; ++b) acc[a][b] = (f32x4){0.f, 0.f, 0.f, 0.f};

  const int lrow = lane >> 2;
  const int lpos = lane & 3;
  const u16* srcK[4];
  #pragma unroll
  for (int i = 0; i < 4; ++i){
    int r = w * 64 + i * 16 + lrow;
    srcK[i] = kt + (size_t)r * 512 + ((lpos ^ ((r >> 1) & 3)) * 8);
  }
  const int rQ = t >> 3;           // 0..63
  const int c4 = (t & 7) * 4;      // 0..28
  const size_t qrow = (size_t)(n0 + rQ) * 512;
  const float rf = rfac[n0 + rQ];
  const int qdst = rQ * 64 + (((c4 >> 3) ^ ((rQ >> 1) & 3)) * 16) + ((c4 & 4) << 1);

  // prologue: tile 0 staged to buf0; q pipeline depth 2
  float4 qcur = *(const float4*)(SMf + qrow + c4);
  {
    char* Qs0 = smem + 65536;
    *(u32*)(Qs0 + qdst)     = pack2(qcur.x, qcur.y);
    *(u32*)(Qs0 + qdst + 4) = pack2(qcur.z, qcur.w);
    float4 cs = *(const float4*)(colsum + c4);
    float4 sq;
    sq.x = qcur.x * rf / cs.x; sq.y = qcur.y * rf / cs.y;
    sq.z = qcur.z * rf / cs.z; sq.w = qcur.w * rf / cs.w;
    *(float4*)(SQ + qrow + c4) = sq;
    char* ldsK = smem + w * 4096;
    #pragma unroll
    for (int i = 0; i < 4; ++i) gload16(ldsK + i * 1024, srcK[i]);
  }
  float4 qnext = *(const float4*)(SMf + qrow + 32 + c4);
  __syncthreads();

  for (int kk = 0; kk < 16; ++kk){
    const int cur = kk & 1;
    if (kk < 15){
      const int nxt = cur ^ 1;
      const int ko = (kk + 1) * 32;
      char* ldsK = smem + nxt * 32768 + w * 4096;
      #pragma unroll
      for (int i = 0; i < 4; ++i) gload16(ldsK + i * 1024, srcK[i] + ko);
      char* QsN = smem + 65536 + nxt * 4096;
      *(u32*)(QsN + qdst)     = pack2(qnext.x, qnext.y);
      *(u32*)(QsN + qdst + 4) = pack2(qnext.z, qnext.w);
      float4 cs = *(const float4*)(colsum + ko + c4);
      float4 sq;
      sq.x = qnext.x * rf / cs.x; sq.y = qnext.y * rf / cs.y;
      sq.z = qnext.z * rf / cs.z; sq.w = qnext.w * rf / cs.w;
      *(float4*)(SQ + qrow + ko + c4) = sq;
      if (kk < 14) qnext = *(const float4*)(SMf + qrow + ko + 32 + c4);
    }
    const char* Ks = smem + cur * 32768;
    const char* Qs = smem + 65536 + cur * 4096;
    bf16x8 af[4], bf[4];
    #pragma unroll
    for (int mi = 0; mi < 4; ++mi){
      int rr = w * 64 + mi * 16 + l15;
      af[mi] = *(const bf16x8*)(Ks + rr * 64 + ((l4 ^ ((rr >> 1) & 3)) * 16));
    }
    #pragma unroll
    for (int nj = 0; nj < 4; ++nj){
      int rb = nj * 16 + l15;
      bf[nj] = *(const bf16x8*)(Qs + rb * 64 + ((l4 ^ ((rb >> 1) & 3)) * 16));
    }
    #pragma unroll
    for (int mi = 0; mi < 4; ++mi)
      #pragma unroll
      for (int nj = 0; nj < 4; ++nj)
        acc[mi][nj] = __builtin_amdgcn_mfma_f32_16x16x32_bf16(af[mi], bf[nj], acc[mi][nj], 0, 0, 0);
    __syncthreads();
  }

  // C row = channel = w*64 + mi*16 + l4*4 + e ; col = pixel = nj*16 + l15.
  const int bq = n0 >> 10;
  const int p0 = n0 & 1023;
  #pragma unroll
  for (int mi = 0; mi < 4; ++mi){
    #pragma unroll
    for (int e = 0; e < 4; ++e){
      const int chn = w * 64 + mi * 16 + l4 * 4 + e;
      float* dst = Uq + (size_t)(bq * 1024 + 512 + chn) * 1024 + p0 + l15;
      #pragma unroll
      for (int nj = 0; nj < 4; ++nj)
        dst[nj * 16] = acc[mi][nj][e];
    }
  }
}

// ---- K9: reduce 1024 per-block loss partials -> scalar f32 outputs.
__global__ __launch_bounds__(256) void k9_fin(const float* __restrict__ part,
    float* __restrict__ outL)
{
  const int t = threadIdx.x;
  float gs = 0.f, ss = 0.f;
  for (int i = t; i < 512; i += 256){ gs += part[2 * i]; ss += part[2 * i + 1]; }
  #pragma unroll
  for (int d = 1; d < 64; d <<= 1){ gs += __shfl_xor(gs, d); ss += __shfl_xor(ss, d); }
  __shared__ float rg[4], rs2[4];
  if ((t & 63) == 0){ rg[t >> 6] = gs; rs2[t >> 6] = ss; }
  __syncthreads();
  if (t == 0){
    float G = rg[0] + rg[1] + rg[2] + rg[3];
    float S = rs2[0] + rs2[1] + rs2[2] + rs2[3];
    outL[0] = G / (65536.0f * 512.0f);
    outL[1] = S / 65536.0f;
  }
}

extern "C" void kernel_launch(void* const* d_in, const int* in_sizes, int n_in,
                              void* d_out, int out_size, void* d_ws, size_t ws_size,
                              hipStream_t stream)
{
  int qi = 0, ki = 1;
  if (n_in >= 2 && in_sizes[0] < in_sizes[1]){ qi = 1; ki = 0; }
  const float* query = (const float*)d_in[qi];
  const float* keys  = (const float*)d_in[ki];
  float* out = (float*)d_out;

  // output offsets (f32 elements)
  const size_t OFF_UQ = 0;
  const size_t OFF_UM = 67108864;
  const size_t OFF_SQ = 67371008;
  const size_t OFF_SM = 100925440;
  const size_t OFF_GL = 134479872;

  // qb bf16 [N][512] parked in first half of the SQ region until K7; K6f overwrites.
  u16* qb = (u16*)(out + OFF_SQ);

  // workspace (~2.1 MB)
  char* ws = (char*)d_ws;
  u16*   kb     = (u16*)ws;                       //   524,288 B
  u16*   kt     = (u16*)(ws + 524288);            //   524,288
  float* sumq   = (float*)(ws + 1048576);         //   262,144
  int*   gidx   = (int*)(ws + 1310720);           //   262,144
  float* s1v    = (float*)(ws + 1572864);         //   262,144
  float* rfac   = (float*)(ws + 1835008);         //   262,144
  float* part   = (float*)(ws + 2097152);         //     4,096 (512 blocks x 2)
  float* kn2    = (float*)(ws + 2105344);         //     2,048
  float* ksum   = (float*)(ws + 2107392);         //     2,048
  u32*   colmax = (u32*)(ws + 2109440);           //     2,048
  float* colsum = (float*)(ws + 2111488);         //     2,048

  k0_prep<<<512, 512, 0, stream>>>(keys, kb, kt, kn2, ksum, colmax, colsum);
  kz_zero<<<4, 256, 0, stream>>>(part);
  k1_norm<<<dim3(16, 64), 256, 0, stream>>>(query, out + OFF_UQ, qb, sumq);
  k2f<<<512, 512, 0, stream>>>(qb, kb, out + OFF_SM, colmax, colsum,
                               gidx, s1v, rfac, kn2, ksum, sumq, part);
  k7_update<<<512, 512, 0, stream>>>(gidx, s1v, colmax, qb, keys, out + OFF_UM);
  k6f<<<1024, 512, 0, stream>>>(out + OFF_SM, kt, out + OFF_UQ, out + OFF_SQ,
                                rfac, colsum);
  k9_fin<<<1, 256, 0, stream>>>(part, out + OFF_GL);
}

// Round 15
// 368.066 us; speedup vs baseline: 1.0985x; 1.0985x over previous
//
#include <hip/hip_runtime.h>
#include <stdint.h>

// B=64, C=512, H=W=32 -> N=65536 pixels, m=512 slots, d=512 dims.
// Inputs f32: query (33,554,432 elems), keys (262,144) -- selected by size.
// Output f32 concat: updated_query [64][1024][32][32] | updated_memory [512][512]
//   | score_query [65536][512] | score_memory [65536][512] | g_loss | s_loss
//
// R15 = R13 exact (measured best: 369.2 us). R14's 128-row K2f tile regressed
// (+35 us: 128-VGPR accumulator -> occupancy drop). Final configuration:
// 64-row full-width fused GEMMs, gload_lds staging, double-buffered,
// one barrier per K-step, vectorized K1.

typedef unsigned int u32;
typedef unsigned long long u64;
typedef unsigned short u16;

typedef float f32x4 __attribute__((ext_vector_type(4)));
typedef short bf16x8 __attribute__((ext_vector_type(8)));

#define DIMS 512

__device__ __forceinline__ u16 f2bf(float x){
  u32 u = __float_as_uint(x);
  return (u16)((u + 0x7FFFu + ((u >> 16) & 1u)) >> 16);
}
__device__ __forceinline__ float bf2f(u16 h){ return __uint_as_float(((u32)h) << 16); }
__device__ __forceinline__ u32 pack2(float a, float b){
  return (u32)f2bf(a) | ((u32)f2bf(b) << 16);
}
__device__ __forceinline__ u32 fkey(float x){
  u32 b = __float_as_uint(x);
  return (b & 0x80000000u) ? ~b : (b | 0x80000000u);
}
__device__ __forceinline__ float fdec(u32 u){
  return (u & 0x80000000u) ? __uint_as_float(u & 0x7FFFFFFFu) : __uint_as_float(~u);
}
// async global->LDS, 16 B per lane (wave-level: LDS dest = base + lane*16)
__device__ __forceinline__ void gload16(char* lds, const void* g){
  __builtin_amdgcn_global_load_lds(
      (const __attribute__((address_space(1))) u32*)g,
      (__attribute__((address_space(3))) u32*)lds, 16, 0, 0);
}

// ---- K0: keys prep. 512 blocks x 512 threads.
__global__ __launch_bounds__(512) void k0_prep(const float* __restrict__ keys,
    u16* __restrict__ kb, u16* __restrict__ kt,
    float* __restrict__ kn2, float* __restrict__ ksum,
    u32* __restrict__ colmax_u, float* __restrict__ colsum)
{
  const int j = blockIdx.x, t = threadIdx.x;
  float v = keys[(size_t)j * 512 + t];
  u16 h = f2bf(v);
  kb[(size_t)j * 512 + t] = h;
  kt[(size_t)t * 512 + j] = h;
  float s = v, ss = v * v;
  #pragma unroll
  for (int d = 1; d < 64; d <<= 1){ s += __shfl_xor(s, d); ss += __shfl_xor(ss, d); }
  __shared__ float rs[8], rss[8];
  const int w = t >> 6, lane = t & 63;
  if (lane == 0){ rs[w] = s; rss[w] = ss; }
  __syncthreads();
  if (t == 0){
    float S = 0.f, SS = 0.f;
    for (int i = 0; i < 8; ++i){ S += rs[i]; SS += rss[i]; }
    ksum[j] = S; kn2[j] = SS;
  }
  if (j == 0){ colmax_u[t] = 0u; colsum[t] = 0.f; }
}

// ---- K1: channel L2-normalize, fully vectorized (float4 over pixels).
// Thread t: pixels px..px+3 (px=(t&15)*4), channels c = (t>>4) + 16k, k=0..31.
__global__ __launch_bounds__(256) void k1_norm(const float* __restrict__ query,
    float* __restrict__ uq, u16* __restrict__ qb, float* __restrict__ sumq)
{
  __shared__ float red[16][64];
  __shared__ float rinvS[64];
  __shared__ float T[64][65];
  const int t = threadIdx.x;
  const int px = (t & 15) * 4;     // 4 consecutive pixels
  const int cg = t >> 4;           // channel base 0..15
  const int b = blockIdx.y;
  const int p0 = blockIdx.x * 64;
  const float* base = query + (size_t)b * 524288 + p0;

  float4 v4[32];
  float ssq0 = 0.f, ssq1 = 0.f, ssq2 = 0.f, ssq3 = 0.f;
  #pragma unroll
  for (int k = 0; k < 32; ++k){
    float4 x = *(const float4*)(base + (size_t)(cg + 16 * k) * 1024 + px);
    v4[k] = x;
    ssq0 += x.x * x.x; ssq1 += x.y * x.y; ssq2 += x.z * x.z; ssq3 += x.w * x.w;
  }
  red[cg][px]     = ssq0;
  red[cg][px + 1] = ssq1;
  red[cg][px + 2] = ssq2;
  red[cg][px + 3] = ssq3;
  __syncthreads();
  if (t < 64){
    float tot = 0.f;
    #pragma unroll
    for (int g = 0; g < 16; ++g) tot += red[g][t];
    rinvS[t] = 1.0f / fmaxf(sqrtf(tot), 1e-12f);
  }
  __syncthreads();
  const float4 ri = *(const float4*)(&rinvS[px]);
  float* uqo = uq + (size_t)b * 1048576 + p0;
  float ms0 = 0.f, ms1 = 0.f, ms2 = 0.f, ms3 = 0.f;
  #pragma unroll
  for (int k = 0; k < 32; ++k){
    float4 x = v4[k];
    x.x *= ri.x; x.y *= ri.y; x.z *= ri.z; x.w *= ri.w;
    v4[k] = x;
    *(float4*)(uqo + (size_t)(cg + 16 * k) * 1024 + px) = x;
    ms0 += x.x; ms1 += x.y; ms2 += x.z; ms3 += x.w;
  }
  // qb transpose: per 64-channel block cb, thread's channels are cc = cg + 16m
  const int r = t >> 2, seg = t & 3;
  for (int cb = 0; cb < 8; ++cb){
    #pragma unroll
    for (int m = 0; m < 4; ++m){
      float4 x = v4[cb * 4 + m];
      float* Trow = &T[cg + 16 * m][px];
      Trow[0] = x.x; Trow[1] = x.y; Trow[2] = x.z; Trow[3] = x.w;
    }
    __syncthreads();
    {
      u32 wpk[8];
      #pragma unroll
      for (int k = 0; k < 8; ++k)
        wpk[k] = pack2(T[seg * 16 + 2 * k][r], T[seg * 16 + 2 * k + 1][r]);
      uint4* dst = (uint4*)(qb + ((size_t)(b * 1024 + p0 + r)) * 512 + cb * 64 + seg * 16);
      dst[0] = make_uint4(wpk[0], wpk[1], wpk[2], wpk[3]);
      dst[1] = make_uint4(wpk[4], wpk[5], wpk[6], wpk[7]);
    }
    __syncthreads();
  }
  red[cg][px]     = ms0;
  red[cg][px + 1] = ms1;
  red[cg][px + 2] = ms2;
  red[cg][px + 3] = ms3;
  __syncthreads();
  if (t < 64){
    float tot = 0.f;
    #pragma unroll
    for (int g = 0; g < 16; ++g) tot += red[g][t];
    sumq[(size_t)b * 1024 + p0 + t] = tot;
  }
}

// ---- K2f: fused score GEMM + row stats + SM + col atomics + losses.
// 1024 blocks x 512 threads (8 waves). 64 N-rows x all 512 slots, BK=32,
// double-buffered LDS, ONE barrier per K-step. Epilogue arrays overlay buffer 0.
__global__ __launch_bounds__(512) void k2f(const u16* __restrict__ Aq,
    const u16* __restrict__ Bk, float* __restrict__ SM,
    u32* __restrict__ colmax_u, float* __restrict__ colsum,
    int* __restrict__ gidx, float* __restrict__ s1v, float* __restrict__ rfac,
    const float* __restrict__ kn2, const float* __restrict__ ksum,
    const float* __restrict__ sumq, float* __restrict__ part)
{
  // layout: As0 @0 (4K), As1 @4096, Bs0 @8192 (32K), Bs1 @40960 (32K)  = 72 KB
  __shared__ __align__(16) char smem[73728];
  const int t = threadIdx.x;
  const int w = t >> 6;
  const int lane = t & 63;
  const int l15 = lane & 15, l4 = lane >> 4;
  const int n0 = blockIdx.x * 64;

  f32x4 acc[4][4];
  #pragma unroll
  for (int a = 0; a < 4; ++a)
    #pragma unroll
    for (int b = 0; b < 4; ++b) acc[a][b] = (f32x4){0.f, 0.f, 0.f, 0.f};

  // per-lane staging sources (pre-swizzled): chunk = 1024 B = 16 rows
  const int lrow = lane >> 2;
  const int lpos = lane & 3;
  const u16* srcB[4];
  #pragma unroll
  for (int i = 0; i < 4; ++i){
    int r = w * 64 + i * 16 + lrow;
    srcB[i] = Bk + (size_t)r * 512 + ((lpos ^ ((r >> 1) & 3)) * 8);
  }
  const u16* srcA;
  {
    int r = (w & 3) * 16 + lrow;
    srcA = Aq + (size_t)(n0 + r) * 512 + ((lpos ^ ((r >> 1) & 3)) * 8);
  }

  // prologue: stage tile 0 -> buf0
  {
    char* ldsB = smem + 8192 + w * 4096;
    #pragma unroll
    for (int i = 0; i < 4; ++i) gload16(ldsB + i * 1024, srcB[i]);
    if (w < 4) gload16(smem + (w & 3) * 1024, srcA);
  }
  __syncthreads();

  for (int kk = 0; kk < 16; ++kk){
    const int cur = kk & 1;
    if (kk < 15){
      const int nxt = cur ^ 1;
      const int ko = (kk + 1) * 32;
      char* ldsB = smem + 8192 + nxt * 32768 + w * 4096;
      #pragma unroll
      for (int i = 0; i < 4; ++i) gload16(ldsB + i * 1024, srcB[i] + ko);
      if (w < 4) gload16(smem + nxt * 4096 + (w & 3) * 1024, srcA + ko);
    }
    const char* As = smem + cur * 4096;
    const char* Bs = smem + 8192 + cur * 32768;
    bf16x8 af[4], bf[4];
    #pragma unroll
    for (int mi = 0; mi < 4; ++mi){
      int rr = mi * 16 + l15;
      af[mi] = *(const bf16x8*)(As + rr * 64 + ((l4 ^ ((rr >> 1) & 3)) * 16));
    }
    #pragma unroll
    for (int nj = 0; nj < 4; ++nj){
      int rb = w * 64 + nj * 16 + l15;
      bf[nj] = *(const bf16x8*)(Bs + rb * 64 + ((l4 ^ ((rb >> 1) & 3)) * 16));
    }
    #pragma unroll
    for (int mi = 0; mi < 4; ++mi)
      #pragma unroll
      for (int nj = 0; nj < 4; ++nj)
        acc[mi][nj] = __builtin_amdgcn_mfma_f32_16x16x32_bf16(af[mi], bf[nj], acc[mi][nj], 0, 0, 0);
    __syncthreads();
  }

  // epilogue LDS overlays buffer-0 region (dead: last K-step read buf1)
  float* rs_m1 = (float*)(smem + 8192);     // [8][64]
  float* rs_m2 = (float*)(smem + 10240);
  float* rs_es = (float*)(smem + 12288);
  int*   rs_i1 = (int*)(smem + 14336);
  int*   rs_i2 = (int*)(smem + 16384);
  float* rtinv = (float*)(smem + 18432);    // [64]

  // acc[mi][nj][e]: row = mi*16 + l4*4 + e (N), col = w*64 + nj*16 + l15 (slot).
  #pragma unroll
  for (int mi = 0; mi < 4; ++mi){
    #pragma unroll
    for (int e = 0; e < 4; ++e){
      const int row = mi * 16 + l4 * 4 + e;
      float m1 = -3e38f, m2 = -3e38f; int i1 = 0x7FFFFFFF, i2 = 0x7FFFFFFF;
      #pragma unroll
      for (int nj = 0; nj < 4; ++nj){
        float val = acc[mi][nj][e];
        int idx = w * 64 + nj * 16 + l15;
        if (val > m1){ m2 = m1; i2 = i1; m1 = val; i1 = idx; }
        else if (val > m2){ m2 = val; i2 = idx; }
      }
      #pragma unroll
      for (int d = 1; d < 16; d <<= 1){
        float o1 = __shfl_xor(m1, d), o2 = __shfl_xor(m2, d);
        int oi1 = __shfl_xor(i1, d), oi2 = __shfl_xor(i2, d);
        if (o1 > m1 || (o1 == m1 && oi1 < i1)){
          if (m1 > o2 || (m1 == o2 && i1 < oi2)){ m2 = m1; i2 = i1; }
          else { m2 = o2; i2 = oi2; }
          m1 = o1; i1 = oi1;
        } else {
          if (o1 > m2 || (o1 == m2 && oi1 < i2)){ m2 = o1; i2 = oi1; }
        }
      }
      if (l15 == 0){
        rs_m1[w * 64 + row] = m1; rs_i1[w * 64 + row] = i1;
        rs_m2[w * 64 + row] = m2; rs_i2[w * 64 + row] = i2;
      }
    }
  }
  #pragma unroll
  for (int nj = 0; nj < 4; ++nj){
    float cm = -3e38f;
    #pragma unroll
    for (int mi = 0; mi < 4; ++mi)
      #pragma unroll
      for (int e = 0; e < 4; ++e) cm = fmaxf(cm, acc[mi][nj][e]);
    cm = fmaxf(cm, __shfl_xor(cm, 16));
    cm = fmaxf(cm, __shfl_xor(cm, 32));
    if (l4 == 0) atomicMax(&colmax_u[w * 64 + nj * 16 + l15], fkey(cm));
  }
  #pragma unroll
  for (int mi = 0; mi < 4; ++mi)
    #pragma unroll
    for (int nj = 0; nj < 4; ++nj)
      #pragma unroll
      for (int e = 0; e < 4; ++e) acc[mi][nj][e] = expf(acc[mi][nj][e]);
  #pragma unroll
  for (int mi = 0; mi < 4; ++mi){
    #pragma unroll
    for (int e = 0; e < 4; ++e){
      const int row = mi * 16 + l4 * 4 + e;
      float ps = acc[mi][0][e] + acc[mi][1][e] + acc[mi][2][e] + acc[mi][3][e];
      #pragma unroll
      for (int d = 1; d < 16; d <<= 1) ps += __shfl_xor(ps, d);
      if (l15 == 0) rs_es[w * 64 + row] = ps;
    }
  }
  #pragma unroll
  for (int nj = 0; nj < 4; ++nj){
    float cs = 0.f;
    #pragma unroll
    for (int mi = 0; mi < 4; ++mi)
      #pragma unroll
      for (int e = 0; e < 4; ++e) cs += acc[mi][nj][e];
    cs += __shfl_xor(cs, 16);
    cs += __shfl_xor(cs, 32);
    if (l4 == 0) atomicAdd(&colsum[w * 64 + nj * 16 + l15], cs);
  }
  __syncthreads();
  if (t < 64){
    const int row = t, n = n0 + row;
    float m1 = -3e38f, m2 = -3e38f; int i1 = 0x7FFFFFFF, i2 = 0x7FFFFFFF;
    float tot = 0.f;
    #pragma unroll
    for (int w2 = 0; w2 < 8; ++w2){
      float o1 = rs_m1[w2 * 64 + row], o2 = rs_m2[w2 * 64 + row];
      int oi1 = rs_i1[w2 * 64 + row], oi2 = rs_i2[w2 * 64 + row];
      tot += rs_es[w2 * 64 + row];
      if (o1 > m1 || (o1 == m1 && oi1 < i1)){
        if (m1 > o2 || (m1 == o2 && i1 < oi2)){ m2 = m1; i2 = i1; }
        else { m2 = o2; i2 = oi2; }
        m1 = o1; i1 = oi1;
      } else {
        if (o1 > m2 || (o1 == m2 && oi1 < i2)){ m2 = o1; i2 = oi1; }
      }
    }
    gidx[n] = i1; s1v[n] = m1; rfac[n] = tot;
    rtinv[row] = 1.0f / tot;
    float sq = sumq[n];
    float gl = 1.0f + kn2[i1] - 2.0f * m1;
    float dp2 = gl + 2e-6f * (sq - ksum[i1]) + 5.12e-10f;
    float dn2 = 1.0f + kn2[i2] - 2.0f * m2 + 2e-6f * (sq - ksum[i2]) + 5.12e-10f;
    float sl = fmaxf(sqrtf(dp2) - sqrtf(dn2) + 1.0f, 0.0f);
    #pragma unroll
    for (int d = 1; d < 64; d <<= 1){ gl += __shfl_xor(gl, d); sl += __shfl_xor(sl, d); }
    if (t == 0){ part[2 * blockIdx.x] = gl; part[2 * blockIdx.x + 1] = sl; }
  }
  __syncthreads();
  #pragma unroll
  for (int mi = 0; mi < 4; ++mi){
    #pragma unroll
    for (int e = 0; e < 4; ++e){
      const int row = mi * 16 + l4 * 4 + e;
      const float ri = rtinv[row];
      float* dst = SM + (size_t)(n0 + row) * 512 + w * 64 + l15;
      #pragma unroll
      for (int nj = 0; nj < 4; ++nj)
        dst[nj * 16] = acc[mi][nj][e] * ri;
    }
  }
}

// ---- K7: memory update, 512 threads (8 waves x 8192 rows). wgt = exp(s1 - cm).
__global__ __launch_bounds__(512) void k7_update(const int* __restrict__ gidx,
    const float* __restrict__ s1v, const u32* __restrict__ colmax_u,
    const u16* __restrict__ qb, const float* __restrict__ keys, float* __restrict__ um)
{
  const int j = blockIdx.x;
  const int t = threadIdx.x;
  const int lane = t & 63;
  const int w = t >> 6;
  const float cm = fdec(colmax_u[j]);
  float acc[8] = {0.f, 0.f, 0.f, 0.f, 0.f, 0.f, 0.f, 0.f};
  const int b0 = w * 8192, b1 = b0 + 8192;
  for (int base = b0; base < b1; base += 64){
    u64 mask = __ballot(gidx[base + lane] == j);
    while (mask){
      int bpos = (int)__builtin_ctzll(mask);
      mask &= mask - 1;
      int rrow = base + bpos;
      float wgt = expf(s1v[rrow] - cm);
      uint4 rv = *(const uint4*)(qb + (size_t)rrow * 512 + lane * 8);
      u32 a4[4] = {rv.x, rv.y, rv.z, rv.w};
      #pragma unroll
      for (int q = 0; q < 4; ++q){
        acc[2 * q]     += wgt * bf2f((u16)(a4[q] & 0xFFFFu));
        acc[2 * q + 1] += wgt * bf2f((u16)(a4[q] >> 16));
      }
    }
  }
  __shared__ float red[512];
  red[t] = 0.f;
  __syncthreads();
  #pragma unroll
  for (int k = 0; k < 8; ++k) atomicAdd(&red[lane * 8 + k], acc[k]);
  __syncthreads();
  float v0 = red[t] + keys[(size_t)j * 512 + t];
  float ssq = v0 * v0;
  #pragma unroll
  for (int d = 1; d < 64; d <<= 1) ssq += __shfl_xor(ssq, d);
  __shared__ float rr8[8];
  if (lane == 0) rr8[w] = ssq;
  __syncthreads();
  float tot = rr8[0] + rr8[1] + rr8[2] + rr8[3] + rr8[4] + rr8[5] + rr8[6] + rr8[7];
  const float rinv = 1.0f / fmaxf(sqrtf(tot), 1e-12f);
  um[(size_t)j * 512 + t] = v0 * rinv;
}

// ---- K6f: concat GEMM + SQ side-write. 1024 blocks x 512 threads, double-buffered,
// one barrier per K-step. A = kt (gload_lds), B = SM f32->bf16 (depth-2 reg pipeline).
__global__ __launch_bounds__(512) void k6f(const float* __restrict__ SMf,
    const u16* __restrict__ kt, float* __restrict__ Uq, float* __restrict__ SQ,
    const float* __restrict__ rfac, const float* __restrict__ colsum)
{
  // Ks0 @0 (32K), Ks1 @32768, Qs0 @65536 (4K), Qs1 @69632  = 72 KB
  __shared__ __align__(16) char smem[73728];
  const int t = threadIdx.x;
  const int w = t >> 6;
  const int lane = t & 63;
  const int l15 = lane & 15, l4 = lane >> 4;
  const int n0 = blockIdx.x * 64;

  f32x4 acc[4][4];
  #pragma unroll
  for (int a = 0; a < 4; ++a)
    #pragma unroll
    for (int b = 0; b < 4; ++b) acc[a][b] = (f32x4){0.f, 0.f, 0.f, 0.f};

  const int lrow = lane >> 2;
  const int lpos = lane & 3;
  const u16* srcK[4];
  #pragma unroll
  for (int i = 0; i < 4; ++i){
    int r = w * 64 + i * 16 + lrow;
    srcK[i] = kt + (size_t)r * 512 + ((lpos ^ ((r >> 1) & 3)) * 8);
  }
  const int rQ = t >> 3;           // 0..63
  const int c4 = (t & 7) * 4;      // 0..28
  const size_t qrow = (size_t)(n0 + rQ) * 512;
  const float rf = rfac[n0 + rQ];
  const int qdst = rQ * 64 + (((c4 >> 3) ^ ((rQ >> 1) & 3)) * 16) + ((c4 & 4) << 1);

  // prologue: tile 0 staged to buf0; q pipeline depth 2
  float4 qcur = *(const float4*)(SMf + qrow + c4);
  {
    char* Qs0 = smem + 65536;
    *(u32*)(Qs0 + qdst)     = pack2(qcur.x, qcur.y);
    *(u32*)(Qs0 + qdst + 4) = pack2(qcur.z, qcur.w);
    float4 cs = *(const float4*)(colsum + c4);
    float4 sq;
    sq.x = qcur.x * rf / cs.x; sq.y = qcur.y * rf / cs.y;
    sq.z = qcur.z * rf / cs.z; sq.w = qcur.w * rf / cs.w;
    *(float4*)(SQ + qrow + c4) = sq;
    char* ldsK = smem + w * 4096;
    #pragma unroll
    for (int i = 0; i < 4; ++i) gload16(ldsK + i * 1024, srcK[i]);
  }
  float4 qnext = *(const float4*)(SMf + qrow + 32 + c4);
  __syncthreads();

  for (int kk = 0; kk < 16; ++kk){
    const int cur = kk & 1;
    if (kk < 15){
      const int nxt = cur ^ 1;
      const int ko = (kk + 1) * 32;
      char* ldsK = smem + nxt * 32768 + w * 4096;
      #pragma unroll
      for (int i = 0; i < 4; ++i) gload16(ldsK + i * 1024, srcK[i] + ko);
      char* QsN = smem + 65536 + nxt * 4096;
      *(u32*)(QsN + qdst)     = pack2(qnext.x, qnext.y);
      *(u32*)(QsN + qdst + 4) = pack2(qnext.z, qnext.w);
      float4 cs = *(const float4*)(colsum + ko + c4);
      float4 sq;
      sq.x = qnext.x * rf / cs.x; sq.y = qnext.y * rf / cs.y;
      sq.z = qnext.z * rf / cs.z; sq.w = qnext.w * rf / cs.w;
      *(float4*)(SQ + qrow + ko + c4) = sq;
      if (kk < 14) qnext = *(const float4*)(SMf + qrow + ko + 32 + c4);
    }
    const char* Ks = smem + cur * 32768;
    const char* Qs = smem + 65536 + cur * 4096;
    bf16x8 af[4], bf[4];
    #pragma unroll
    for (int mi = 0; mi < 4; ++mi){
      int rr = w * 64 + mi * 16 + l15;
      af[mi] = *(const bf16x8*)(Ks + rr * 64 + ((l4 ^ ((rr >> 1) & 3)) * 16));
    }
    #pragma unroll
    for (int nj = 0; nj < 4; ++nj){
      int rb = nj * 16 + l15;
      bf[nj] = *(const bf16x8*)(Qs + rb * 64 + ((l4 ^ ((rb >> 1) & 3)) * 16));
    }
    #pragma unroll
    for (int mi = 0; mi < 4; ++mi)
      #pragma unroll
      for (int nj = 0; nj < 4; ++nj)
        acc[mi][nj] = __builtin_amdgcn_mfma_f32_16x16x32_bf16(af[mi], bf[nj], acc[mi][nj], 0, 0, 0);
    __syncthreads();
  }

  // C row = channel = w*64 + mi*16 + l4*4 + e ; col = pixel = nj*16 + l15.
  const int bq = n0 >> 10;
  const int p0 = n0 & 1023;
  #pragma unroll
  for (int mi = 0; mi < 4; ++mi){
    #pragma unroll
    for (int e = 0; e < 4; ++e){
      const int chn = w * 64 + mi * 16 + l4 * 4 + e;
      float* dst = Uq + (size_t)(bq * 1024 + 512 + chn) * 1024 + p0 + l15;
      #pragma unroll
      for (int nj = 0; nj < 4; ++nj)
        dst[nj * 16] = acc[mi][nj][e];
    }
  }
}

// ---- K9: reduce 1024 per-block loss partials -> scalar f32 outputs.
__global__ __launch_bounds__(256) void k9_fin(const float* __restrict__ part,
    float* __restrict__ outL)
{
  const int t = threadIdx.x;
  float gs = 0.f, ss = 0.f;
  for (int i = t; i < 1024; i += 256){ gs += part[2 * i]; ss += part[2 * i + 1]; }
  #pragma unroll
  for (int d = 1; d < 64; d <<= 1){ gs += __shfl_xor(gs, d); ss += __shfl_xor(ss, d); }
  __shared__ float rg[4], rs2[4];
  if ((t & 63) == 0){ rg[t >> 6] = gs; rs2[t >> 6] = ss; }
  __syncthreads();
  if (t == 0){
    float G = rg[0] + rg[1] + rg[2] + rg[3];
    float S = rs2[0] + rs2[1] + rs2[2] + rs2[3];
    outL[0] = G / (65536.0f * 512.0f);
    outL[1] = S / 65536.0f;
  }
}

extern "C" void kernel_launch(void* const* d_in, const int* in_sizes, int n_in,
                              void* d_out, int out_size, void* d_ws, size_t ws_size,
                              hipStream_t stream)
{
  int qi = 0, ki = 1;
  if (n_in >= 2 && in_sizes[0] < in_sizes[1]){ qi = 1; ki = 0; }
  const float* query = (const float*)d_in[qi];
  const float* keys  = (const float*)d_in[ki];
  float* out = (float*)d_out;

  // output offsets (f32 elements)
  const size_t OFF_UQ = 0;
  const size_t OFF_UM = 67108864;
  const size_t OFF_SQ = 67371008;
  const size_t OFF_SM = 100925440;
  const size_t OFF_GL = 134479872;

  // qb bf16 [N][512] parked in first half of the SQ region until K7; K6f overwrites.
  u16* qb = (u16*)(out + OFF_SQ);

  // workspace (~2.1 MB)
  char* ws = (char*)d_ws;
  u16*   kb     = (u16*)ws;                       //   524,288 B
  u16*   kt     = (u16*)(ws + 524288);            //   524,288
  float* sumq   = (float*)(ws + 1048576);         //   262,144
  int*   gidx   = (int*)(ws + 1310720);           //   262,144
  float* s1v    = (float*)(ws + 1572864);         //   262,144
  float* rfac   = (float*)(ws + 1835008);         //   262,144
  float* part   = (float*)(ws + 2097152);         //     8,192
  float* kn2    = (float*)(ws + 2105344);         //     2,048
  float* ksum   = (float*)(ws + 2107392);         //     2,048
  u32*   colmax = (u32*)(ws + 2109440);           //     2,048
  float* colsum = (float*)(ws + 2111488);         //     2,048

  k0_prep<<<512, 512, 0, stream>>>(keys, kb, kt, kn2, ksum, colmax, colsum);
  k1_norm<<<dim3(16, 64), 256, 0, stream>>>(query, out + OFF_UQ, qb, sumq);
  k2f<<<1024, 512, 0, stream>>>(qb, kb, out + OFF_SM, colmax, colsum,
                                gidx, s1v, rfac, kn2, ksum, sumq, part);
  k7_update<<<512, 512, 0, stream>>>(gidx, s1v, colmax, qb, keys, out + OFF_UM);
  k6f<<<1024, 512, 0, stream>>>(out + OFF_SM, kt, out + OFF_UQ, out + OFF_SQ,
                                rfac, colsum);
  k9_fin<<<1, 256, 0, stream>>>(part, out + OFF_GL);
}